// Round 11
// baseline (150.505 us; speedup 1.0000x reference)
//
#include <hip/hip_runtime.h>

typedef __bf16 bf16;
typedef __bf16 bf16x8 __attribute__((ext_vector_type(8)));
typedef float f32x4 __attribute__((ext_vector_type(4)));
typedef float f32x16 __attribute__((ext_vector_type(16)));

#define MFMA16(a, b, c) __builtin_amdgcn_mfma_f32_16x16x32_bf16(a, b, c, 0, 0, 0)
#define MFMA32(a, b, c) __builtin_amdgcn_mfma_f32_32x32x16_bf16(a, b, c, 0, 0, 0)

// scale (1/sqrt(64)) * log2(e), folded into q at the QKV epilogue.
#define QSCALE 0.1803368801111137f

static __device__ __forceinline__ unsigned int pack2(float a, float b) {
  unsigned short s0 = __builtin_bit_cast(unsigned short, (bf16)a);
  unsigned short s1 = __builtin_bit_cast(unsigned short, (bf16)b);
  return (unsigned int)s0 | ((unsigned int)s1 << 16);
}

// Single-instruction HW 2^x (v_exp_f32, ~1 ULP). Plain __builtin_exp2f
// without fast-math lowers to the OCML libcall -- R10 measured this swap as
// a real win (-1.7us).
static __device__ __forceinline__ float fexp2(float x) {
#if __has_builtin(__builtin_amdgcn_exp2f)
  return __builtin_amdgcn_exp2f(x);
#else
  float r;
  asm("v_exp_f32 %0, %1" : "=v"(r) : "v"(x));
  return r;
#endif
}

// async global->LDS, 16B per lane. LDS dest is wave-uniform base + lane*16.
static __device__ __forceinline__ void gl16(const bf16* g, bf16* l) {
  __builtin_amdgcn_global_load_lds(
      (const __attribute__((address_space(1))) unsigned int*)g,
      (__attribute__((address_space(3))) unsigned int*)l, 16, 0, 0);
}

// ---------------------------------------------------------------------------
// Fused preprocessing: blocks [0,1024) convert qkv_w/proj_w fp32->bf16;
// blocks [1024,1536) LayerNorm x (B=8,C=512,HW=1024) fp32 -> xn (B*HW,C) bf16.
// ---------------------------------------------------------------------------
__global__ __launch_bounds__(256) void prep_kernel(
    const float* __restrict__ qkvw, const float* __restrict__ projw,
    bf16* __restrict__ wc, const float* __restrict__ x,
    const float* __restrict__ lnw, const float* __restrict__ lnb,
    bf16* __restrict__ xn) {
  __shared__ float tile[512 * 17];  // 34816 B (ln path only)
  __shared__ float wsh[512];
  __shared__ float bsh[512];
  const int t = threadIdx.x;
  if (blockIdx.x < 1024) {
    // ---- weight convert path ----
    int c4 = blockIdx.x * 256 + t;  // 0..262143
    const float* src = (c4 < 196608) ? (qkvw + (size_t)c4 * 4)
                                     : (projw + (size_t)(c4 - 196608) * 4);
    float4 v = *(const float4*)src;
    uint2 o;
    o.x = pack2(v.x, v.y);
    o.y = pack2(v.z, v.w);
    *(uint2*)&wc[(size_t)c4 * 4] = o;
    return;
  }
  // ---- layernorm path ----
  const int bid = blockIdx.x - 1024;
  const int b = bid >> 6;          // 8 batches
  const int p0 = (bid & 63) * 16;  // 64 pixel groups of 16
  for (int i = t; i < 512; i += 256) {
    wsh[i] = lnw[i];
    bsh[i] = lnb[i];
  }
  const float* xb = x + (size_t)b * 524288 + p0;
#pragma unroll
  for (int i = 0; i < 8; ++i) {
    int chunk = t + 256 * i;  // 2048 float4 chunks = 512 rows x 4
    int c = chunk >> 2, px4 = (chunk & 3) * 4;
    float4 v = *(const float4*)&xb[(size_t)c * 1024 + px4];
    tile[c * 17 + px4 + 0] = v.x;
    tile[c * 17 + px4 + 1] = v.y;
    tile[c * 17 + px4 + 2] = v.z;
    tile[c * 17 + px4 + 3] = v.w;
  }
  __syncthreads();
  const int pix = t >> 4, j = t & 15;  // 16 threads per pixel
  float sum = 0.f, sq = 0.f;
#pragma unroll
  for (int i = 0; i < 32; ++i) {
    int c = i * 16 + j;
    float v = tile[c * 17 + pix];
    sum += v;
    sq += v * v;
  }
#pragma unroll
  for (int m = 1; m <= 8; m <<= 1) {
    sum += __shfl_xor(sum, m);
    sq += __shfl_xor(sq, m);
  }
  float mu = sum * (1.f / 512.f);
  float var = sq * (1.f / 512.f) - mu * mu;
  float rstd = rsqrtf(var + 1e-5f);
  unsigned int* orow =
      (unsigned int*)(xn + ((size_t)(b * 1024 + p0 + pix)) * 512);
#pragma unroll
  for (int i = 0; i < 16; ++i) {
    int dw = i * 16 + j;  // dword index 0..255
    int c0 = 2 * dw, c1 = 2 * dw + 1;
    float v0 = (tile[c0 * 17 + pix] - mu) * rstd * wsh[c0] + bsh[c0];
    float v1 = (tile[c1 * 17 + pix] - mu) * rstd * wsh[c1] + bsh[c1];
    orow[dw] = pack2(v0, v1);
  }
}

// ---------------------------------------------------------------------------
// QKV GEMM: C = A * B^T, A=xn (8192x512), B=qkv_w (1536x512). Tile 128x128,
// BK=32, double-buffered global_load_lds staging, one barrier/iter.
// LDS granule swizzle (both-sides-or-neither): chunk (r, g) stores the
// global granule g ^ f(r), f(r) = (r>>1)&3, via pre-swizzled SOURCE address;
// fragment reads fetch slot (quad ^ f(row)).
// Epilogue: +bias, q pre-scaled by QSCALE; q/k scattered (b,h,p,d); V blocks
// transposed through LDS then stored as coalesced 128B vT rows (b,h,d,p).
// vT COLUMN ORDER IS PERMUTED: within each 16-pixel group, p-bit2 and p-bit3
// are swapped (stored order {0-3,8-11,4-7,12-15}). This makes the attention
// PV B-fragment (k = (lane>>5)*8+j of mfma_32x32x16) line up with the
// Sᵀ C-layout (row=(reg&3)+8*(reg>>2)+4*(lane>>5)) with no cross-lane moves.
// ---------------------------------------------------------------------------
__global__ __launch_bounds__(256, 3) void gemm_qkv(
    const bf16* __restrict__ A, const bf16* __restrict__ Bm,
    const float* __restrict__ bias, bf16* __restrict__ oq,
    bf16* __restrict__ okk, bf16* __restrict__ ov) {
  // layout: A buf0 [0,4096), A buf1 [4096,8192), B buf0 [8192,12288),
  // B buf1 [12288,16384). Reused whole as V-transpose scratch in epilogue.
  __shared__ bf16 smem[16384];  // 32KB
  const int t = threadIdx.x;
  const int lane = t & 63, w = t >> 6;
  const int quad = lane >> 4, r16 = lane & 15;
  const int wm = w >> 1, wn = w & 1;
  // panel swizzle: 8 m-tiles x 12 n-tiles per panel
  const int pid = blockIdx.x;
  const int panel = pid / 96, within = pid % 96;
  const int m0 = (panel * 8 + (within & 7)) * 128;
  const int n0 = (within >> 3) * 128;
  int sr[2], sc[2];
#pragma unroll
  for (int j = 0; j < 2; ++j) {
    int c = (w * 2 + j) * 64 + lane;
    int r = c >> 2, g = c & 3;
    sr[j] = r;                         // row 0..127
    sc[j] = (g ^ ((r >> 1) & 3)) * 8;  // pre-swizzled source granule
  }
  const int gx = (r16 >> 1) & 3;  // lane-uniform read-side granule xor
  f32x4 acc[4][4] = {};
  // prologue: stage k-tile 0 into buffer 0
#pragma unroll
  for (int j = 0; j < 2; ++j) {
    gl16(&A[(size_t)(m0 + sr[j]) * 512 + sc[j]], &smem[(w * 2 + j) * 512]);
    gl16(&Bm[(size_t)(n0 + sr[j]) * 512 + sc[j]],
         &smem[8192 + (w * 2 + j) * 512]);
  }
  __syncthreads();
  for (int it = 0; it < 16; ++it) {
    const int cur = it & 1, nxt = cur ^ 1;
    if (it < 15) {
      int k1 = (it + 1) * 32;
#pragma unroll
      for (int j = 0; j < 2; ++j) {
        gl16(&A[(size_t)(m0 + sr[j]) * 512 + k1 + sc[j]],
             &smem[nxt * 4096 + (w * 2 + j) * 512]);
        gl16(&Bm[(size_t)(n0 + sr[j]) * 512 + k1 + sc[j]],
             &smem[8192 + nxt * 4096 + (w * 2 + j) * 512]);
      }
    }
    const bf16* ac = &smem[cur * 4096];
    const bf16* bc = &smem[8192 + cur * 4096];
    bf16x8 af[4], bfr[4];
#pragma unroll
    for (int i = 0; i < 4; ++i) {
      int row = wm * 64 + i * 16 + r16;
      af[i] = *(const bf16x8*)&ac[row * 32 + (quad ^ gx) * 8];
    }
#pragma unroll
    for (int i = 0; i < 4; ++i) {
      int row = wn * 64 + i * 16 + r16;
      bfr[i] = *(const bf16x8*)&bc[row * 32 + (quad ^ gx) * 8];
    }
#pragma unroll
    for (int tm = 0; tm < 4; ++tm)
#pragma unroll
      for (int tn = 0; tn < 4; ++tn)
        acc[tm][tn] = MFMA16(af[tm], bfr[tn], acc[tm][tn]);
    __syncthreads();
  }
  if (n0 < 1024) {
    // q / k blocks: direct scatter (d-contiguous 32B segments)
#pragma unroll
    for (int tm = 0; tm < 4; ++tm) {
#pragma unroll
      for (int tn = 0; tn < 4; ++tn) {
        int n = n0 + wn * 64 + tn * 16 + r16;
        float bn = bias[n];
        int comp = n >> 9, h = (n >> 6) & 7, d = n & 63;
#pragma unroll
        for (int r = 0; r < 4; ++r) {
          int m = m0 + wm * 64 + tm * 16 + quad * 4 + r;
          float v = acc[tm][tn][r] + bn;
          int b = m >> 10, p = m & 1023;
          size_t base = ((size_t)(b * 8 + h)) * 65536;
          if (comp == 0)
            oq[base + (size_t)p * 64 + d] = (bf16)(v * QSCALE);
          else
            okk[base + (size_t)p * 64 + d] = (bf16)v;
        }
      }
    }
  } else {
    // V block: per-wave LDS transpose (64d x 64p, stride 64, xor-swizzled at
    // 8-elem granules) then coalesced 128B-row stores of vT (b,h,d,p).
    // p-bit2<->bit3 column permutation baked in (granule tm*2+(quad&1),
    // offset (quad>>1)*4).
    bf16* tb = &smem[w * 4096];
#pragma unroll
    for (int tn = 0; tn < 4; ++tn) {
      int n = n0 + wn * 64 + tn * 16 + r16;
      float bn = bias[n];
      int row = tn * 16 + r16;  // d_local
#pragma unroll
      for (int tm = 0; tm < 4; ++tm) {
        f32x4 a = acc[tm][tn];
        uint2 pk;
        pk.x = pack2(a[0] + bn, a[1] + bn);
        pk.y = pack2(a[2] + bn, a[3] + bn);
        int g = (tm * 2 + (quad & 1)) ^ (row & 7);
        *(uint2*)&tb[row * 64 + g * 8 + (quad >> 1) * 4] = pk;
      }
    }
    // wave-private region: no barrier needed (lgkmcnt orders write->read)
    const int h = ((n0 - 1024) >> 6) + wn;
    const int mw = m0 + wm * 64;
    const int b = mw >> 10;
    bf16* vbase = ov + ((size_t)(b * 8 + h)) * 65536 + (mw & 1023);
#pragma unroll
    for (int pass = 0; pass < 8; ++pass) {
      int row = pass * 8 + (lane >> 3);
      int g = (lane & 7) ^ (row & 7);
      uint4 vd = *(uint4*)&tb[row * 64 + g * 8];
      *(uint4*)&vbase[(size_t)row * 1024 + (lane & 7) * 8] = vd;
    }
  }
}

// ---------------------------------------------------------------------------
// Proj GEMM: C = W * A^T, W=proj_w (512x512), A=attn out (8192x512).
// Tile 64x64 (grid 8x128 = 1024 blocks), BK=64, double-buffered swizzled
// global_load_lds staging. Epilogue: +bias[m] +residual, fp32 out (B,C,HW).
// ---------------------------------------------------------------------------
__global__ __launch_bounds__(256, 4) void gemm_proj(
    const bf16* __restrict__ Wm, const bf16* __restrict__ A,
    const float* __restrict__ bias, const float* __restrict__ resid,
    float* __restrict__ op) {
  __shared__ bf16 ash[2][64 * 64];
  __shared__ bf16 bsh[2][64 * 64];
  const int t = threadIdx.x;
  const int lane = t & 63, w = t >> 6;
  const int quad = lane >> 4, r16 = lane & 15;
  const int wm = w >> 1, wn = w & 1;
  const int m0 = blockIdx.x * 64, n0 = blockIdx.y * 64;
  int soff[2], sr[2];
#pragma unroll
  for (int j = 0; j < 2; ++j) {
    int c = (w * 2 + j) * 64 + lane;
    int r = c >> 3, cc = c & 7;
    sr[j] = r;
    soff[j] = (cc ^ (r & 7)) * 8;
  }
  f32x4 acc[2][2] = {};
  // prologue: stage k-tile 0 into buffer 0
#pragma unroll
  for (int j = 0; j < 2; ++j) {
    gl16(&Wm[(size_t)(m0 + sr[j]) * 512 + soff[j]], &ash[0][(w * 2 + j) * 512]);
    gl16(&A[(size_t)(n0 + sr[j]) * 512 + soff[j]], &bsh[0][(w * 2 + j) * 512]);
  }
  __syncthreads();
  for (int it = 0; it < 8; ++it) {
    const int cur = it & 1, nxt = cur ^ 1;
    if (it < 7) {
      int k1 = (it + 1) * 64;
#pragma unroll
      for (int j = 0; j < 2; ++j) {
        gl16(&Wm[(size_t)(m0 + sr[j]) * 512 + k1 + soff[j]],
             &ash[nxt][(w * 2 + j) * 512]);
        gl16(&A[(size_t)(n0 + sr[j]) * 512 + k1 + soff[j]],
             &bsh[nxt][(w * 2 + j) * 512]);
      }
    }
#pragma unroll
    for (int kc = 0; kc < 2; ++kc) {
      bf16x8 af[2], bfr[2];
#pragma unroll
      for (int i = 0; i < 2; ++i) {
        int row = wm * 32 + i * 16 + r16;
        af[i] = *(const bf16x8*)&ash[cur][row * 64 +
                                          ((kc * 4 + quad) ^ (r16 & 7)) * 8];
      }
#pragma unroll
      for (int i = 0; i < 2; ++i) {
        int row = wn * 32 + i * 16 + r16;
        bfr[i] = *(const bf16x8*)&bsh[cur][row * 64 +
                                           ((kc * 4 + quad) ^ (r16 & 7)) * 8];
      }
#pragma unroll
      for (int tm = 0; tm < 2; ++tm)
#pragma unroll
        for (int tn = 0; tn < 2; ++tn)
          acc[tm][tn] = MFMA16(af[tm], bfr[tn], acc[tm][tn]);
    }
    __syncthreads();
  }
#pragma unroll
  for (int tm = 0; tm < 2; ++tm) {
#pragma unroll
    for (int tn = 0; tn < 2; ++tn) {
      int n = n0 + wn * 32 + tn * 16 + r16;
      int b = n >> 10, p = n & 1023;
#pragma unroll
      for (int r = 0; r < 4; ++r) {
        int m = m0 + wm * 32 + tm * 16 + quad * 4 + r;
        size_t idx = ((size_t)(b * 512 + m)) * 1024 + p;
        op[idx] = acc[tm][tn][r] + bias[m] + resid[idx];
      }
    }
  }
}

// ---------------------------------------------------------------------------
// Flash attention, 32x32x16-MFMA, 32 q-rows/wave, fexp2 softmax (R10 win).
// THIS ROUND: 2-wave blocks (128 thr, 64q) + grid (64 bh, 16 qt) = 1024
// blocks. Per CU: 5 blocks (LDS-capped at 5x32KB = 160KB) = 10 waves in 5
// INDEPENDENT 2-wave barrier domains, vs R4's 8 waves in 2 4-wave domains --
// barrier rendezvous is cheaper and one block's staging drain overlaps four
// other blocks' compute. Per-wave inner loop identical to R4/R10.
// Swapped QK^T: S^T = mfma(K, Q) puts q = lane&31; softmax fully
// in-register. Grid x = bh: id%8 = bh%8 keeps one bh's K/V on one XCD L2.
// ---------------------------------------------------------------------------
__global__ __launch_bounds__(128, 2) void attn_kernel(
    const bf16* __restrict__ q, const bf16* __restrict__ k,
    const bf16* __restrict__ vT, bf16* __restrict__ o) {
  __shared__ bf16 kt[2][64 * 64];  // 2x8KB K tiles (kv-row major, swizzled)
  __shared__ bf16 vt[2][64 * 64];  // 2x8KB vT tiles (d-row major, swizzled)
  const int t = threadIdx.x;
  const int lane = t & 63, w = t >> 6;  // 2 waves
  const int l31 = lane & 31, hi = lane >> 5;
  const int bh = blockIdx.x;
  const int qt0 = blockIdx.y * 64;
  const bf16* qb = q + (size_t)bh * 65536;
  const bf16* kb = k + (size_t)bh * 65536;
  const bf16* vb = vT + (size_t)bh * 65536;
  // Q as B-fragment: col = q = lane&31, k(=d) = ks*16 + hi*8 + j
  const int qrow = qt0 + w * 32 + l31;
  bf16x8 qf[4];
#pragma unroll
  for (int ks = 0; ks < 4; ++ks)
    qf[ks] = *(const bf16x8*)&qb[(size_t)qrow * 64 + ks * 16 + hi * 8];
  // staging: 512 chunks/tile; wave w issues j=0..3; chunk c=(w*4+j)*64+lane
  int offk[4], offv[4];
#pragma unroll
  for (int j = 0; j < 4; ++j) {
    int c = (w * 4 + j) * 64 + lane;
    int r = c >> 3, cc = c & 7;
    int sw = (cc ^ (r & 7)) * 8;
    offk[j] = r * 64 + sw;    // K: row=kv (stride 64)
    offv[j] = r * 1024 + sw;  // vT: row=d (stride 1024)
  }
  f32x16 oacc[2] = {};  // O[q=(reg&3)+8*(reg>>2)+4*hi][d=mf*32+l31]
  float rsum = 0.f;     // full exp row-sum for q=l31 (this hi-half's kv)
  const int swz = l31 & 7;
  // prologue: stage tile 0
#pragma unroll
  for (int j = 0; j < 4; ++j) {
    gl16(&kb[offk[j]], &kt[0][(w * 4 + j) * 512]);
    gl16(&vb[offv[j]], &vt[0][(w * 4 + j) * 512]);
  }
  __syncthreads();
  for (int it = 0; it < 16; ++it) {
    const int cur = it & 1, nxt = cur ^ 1;
    if (it < 15) {
      int kv1 = (it + 1) * 64;
#pragma unroll
      for (int j = 0; j < 4; ++j) {
        gl16(&kb[(size_t)kv1 * 64 + offk[j]], &kt[nxt][(w * 4 + j) * 512]);
        gl16(&vb[(size_t)kv1 + offv[j]], &vt[nxt][(w * 4 + j) * 512]);
      }
    }
    const bf16* ktc = kt[cur];
    const bf16* vtc = vt[cur];
    // S^T[kv][q] = sum_d K[kv][d] Q[q][d]: two 32-kv tiles, 4 k-steps each.
    f32x16 sT[2] = {};
#pragma unroll
    for (int T = 0; T < 2; ++T) {
      const bf16* kr = &ktc[(T * 32 + l31) * 64];
#pragma unroll
      for (int ks = 0; ks < 4; ++ks) {
        bf16x8 kf = *(const bf16x8*)&kr[((ks * 2 + hi) ^ swz) * 8];
        sT[T] = MFMA32(kf, qf[ks], sT[T]);
      }
    }
    // max-free softmax numerator, all in-register (q = l31 for every reg)
#pragma unroll
    for (int T = 0; T < 2; ++T)
#pragma unroll
      for (int r = 0; r < 16; ++r) {
        float p = fexp2(sT[T][r]);
        sT[T][r] = p;
        rsum += p;
      }
    // PV: 4 chunks of 16 kv. P A-frag packs straight from regs; its k-slot
    // order (hi=0:{0-3,8-11}, hi=1:{4-7,12-15}) matches the permuted vT.
#pragma unroll
    for (int c4 = 0; c4 < 4; ++c4) {
      const int T = c4 >> 1, b0 = (c4 & 1) * 8;
      uint4 pui;
      pui.x = pack2(sT[T][b0 + 0], sT[T][b0 + 1]);
      pui.y = pack2(sT[T][b0 + 2], sT[T][b0 + 3]);
      pui.z = pack2(sT[T][b0 + 4], sT[T][b0 + 5]);
      pui.w = pack2(sT[T][b0 + 6], sT[T][b0 + 7]);
      bf16x8 pf = __builtin_bit_cast(bf16x8, pui);
#pragma unroll
      for (int mf = 0; mf < 2; ++mf) {
        const bf16* vr = &vtc[(mf * 32 + l31) * 64];
        bf16x8 vf = *(const bf16x8*)&vr[((c4 * 2 + hi) ^ swz) * 8];
        oacc[mf] = MFMA32(pf, vf, oacc[mf]);
      }
    }
    __syncthreads();  // both waves done with cur before it's restaged
  }
  // combine the two hi-half partial row sums (same q = l31)
  rsum += __shfl_xor(rsum, 32);
  float inv = 1.f / rsum;
  const int b = bh >> 3, h = bh & 7;
#pragma unroll
  for (int r = 0; r < 16; ++r) {
    const int ql = (r & 3) + 8 * (r >> 2) + 4 * hi;
    float invq = __shfl(inv, ql);  // lane ql holds inv for q-row ql
    const int p = qt0 + w * 32 + ql;
    const size_t base = ((size_t)(b * 1024 + p)) * 512 + h * 64;
#pragma unroll
    for (int mf = 0; mf < 2; ++mf)
      o[base + mf * 32 + l31] = (bf16)(oacc[mf][r] * invq);
  }
}

// ---------------------------------------------------------------------------
extern "C" void kernel_launch(void* const* d_in, const int* in_sizes, int n_in,
                              void* d_out, int out_size, void* d_ws,
                              size_t ws_size, hipStream_t stream) {
  (void)in_sizes;
  (void)n_in;
  (void)out_size;
  (void)ws_size;
  const float* x = (const float*)d_in[0];
  const float* lnw = (const float*)d_in[1];
  const float* lnb = (const float*)d_in[2];
  const float* qkvw = (const float*)d_in[3];
  const float* qkvb = (const float*)d_in[4];
  const float* projw = (const float*)d_in[5];
  const float* projb = (const float*)d_in[6];
  float* out = (float*)d_out;

  const size_t NELEM = 4194304;  // 8192 * 512
  bf16* wc = (bf16*)d_ws;        // qkvw_c [0,786432) projw_c [786432,1048576)
  bf16* xn = wc + 1048576;       // 8 MB; reused as attention output
  bf16* qws = xn + NELEM;        // 8 MB
  bf16* kws = qws + NELEM;       // 8 MB
  bf16* vws = kws + NELEM;       // 8 MB (transposed+col-permuted: b,h,d,p')
  bf16* aws = xn;                // reuse: xn dead after QKV gemm

  prep_kernel<<<dim3(1536), dim3(256), 0, stream>>>(qkvw, projw, wc, x, lnw,
                                                    lnb, xn);
  gemm_qkv<<<dim3(768), dim3(256), 0, stream>>>(xn, wc, qkvb, qws, kws, vws);
  attn_kernel<<<dim3(64, 16), dim3(128), 0, stream>>>(qws, kws, vws, aws);
  gemm_proj<<<dim3(8, 128), dim3(256), 0, stream>>>(wc + 786432, aws, projb, x,
                                                    out);
}

// Round 12
// 148.569 us; speedup vs baseline: 1.0130x; 1.0130x over previous
//
#include <hip/hip_runtime.h>

typedef __bf16 bf16;
typedef __bf16 bf16x8 __attribute__((ext_vector_type(8)));
typedef float f32x4 __attribute__((ext_vector_type(4)));
typedef float f32x16 __attribute__((ext_vector_type(16)));

#define MFMA16(a, b, c) __builtin_amdgcn_mfma_f32_16x16x32_bf16(a, b, c, 0, 0, 0)
#define MFMA32(a, b, c) __builtin_amdgcn_mfma_f32_32x32x16_bf16(a, b, c, 0, 0, 0)

// scale (1/sqrt(64)) * log2(e), folded into q at the QKV epilogue.
#define QSCALE 0.1803368801111137f

static __device__ __forceinline__ unsigned int pack2(float a, float b) {
  unsigned short s0 = __builtin_bit_cast(unsigned short, (bf16)a);
  unsigned short s1 = __builtin_bit_cast(unsigned short, (bf16)b);
  return (unsigned int)s0 | ((unsigned int)s1 << 16);
}

// Single-instruction HW 2^x (v_exp_f32, ~1 ULP). Plain __builtin_exp2f
// without fast-math lowers to the OCML libcall -- R10 measured this swap as
// a real win (-1.7us on total).
static __device__ __forceinline__ float fexp2(float x) {
#if __has_builtin(__builtin_amdgcn_exp2f)
  return __builtin_amdgcn_exp2f(x);
#else
  float r;
  asm("v_exp_f32 %0, %1" : "=v"(r) : "v"(x));
  return r;
#endif
}

// async global->LDS, 16B per lane. LDS dest is wave-uniform base + lane*16.
static __device__ __forceinline__ void gl16(const bf16* g, bf16* l) {
  __builtin_amdgcn_global_load_lds(
      (const __attribute__((address_space(1))) unsigned int*)g,
      (__attribute__((address_space(3))) unsigned int*)l, 16, 0, 0);
}

// ---------------------------------------------------------------------------
// Fused preprocessing: blocks [0,1024) convert qkv_w/proj_w fp32->bf16;
// blocks [1024,1536) LayerNorm x (B=8,C=512,HW=1024) fp32 -> xn (B*HW,C) bf16.
// ---------------------------------------------------------------------------
__global__ __launch_bounds__(256) void prep_kernel(
    const float* __restrict__ qkvw, const float* __restrict__ projw,
    bf16* __restrict__ wc, const float* __restrict__ x,
    const float* __restrict__ lnw, const float* __restrict__ lnb,
    bf16* __restrict__ xn) {
  __shared__ float tile[512 * 17];  // 34816 B (ln path only)
  __shared__ float wsh[512];
  __shared__ float bsh[512];
  const int t = threadIdx.x;
  if (blockIdx.x < 1024) {
    // ---- weight convert path ----
    int c4 = blockIdx.x * 256 + t;  // 0..262143
    const float* src = (c4 < 196608) ? (qkvw + (size_t)c4 * 4)
                                     : (projw + (size_t)(c4 - 196608) * 4);
    float4 v = *(const float4*)src;
    uint2 o;
    o.x = pack2(v.x, v.y);
    o.y = pack2(v.z, v.w);
    *(uint2*)&wc[(size_t)c4 * 4] = o;
    return;
  }
  // ---- layernorm path ----
  const int bid = blockIdx.x - 1024;
  const int b = bid >> 6;          // 8 batches
  const int p0 = (bid & 63) * 16;  // 64 pixel groups of 16
  for (int i = t; i < 512; i += 256) {
    wsh[i] = lnw[i];
    bsh[i] = lnb[i];
  }
  const float* xb = x + (size_t)b * 524288 + p0;
#pragma unroll
  for (int i = 0; i < 8; ++i) {
    int chunk = t + 256 * i;  // 2048 float4 chunks = 512 rows x 4
    int c = chunk >> 2, px4 = (chunk & 3) * 4;
    float4 v = *(const float4*)&xb[(size_t)c * 1024 + px4];
    tile[c * 17 + px4 + 0] = v.x;
    tile[c * 17 + px4 + 1] = v.y;
    tile[c * 17 + px4 + 2] = v.z;
    tile[c * 17 + px4 + 3] = v.w;
  }
  __syncthreads();
  const int pix = t >> 4, j = t & 15;  // 16 threads per pixel
  float sum = 0.f, sq = 0.f;
#pragma unroll
  for (int i = 0; i < 32; ++i) {
    int c = i * 16 + j;
    float v = tile[c * 17 + pix];
    sum += v;
    sq += v * v;
  }
#pragma unroll
  for (int m = 1; m <= 8; m <<= 1) {
    sum += __shfl_xor(sum, m);
    sq += __shfl_xor(sq, m);
  }
  float mu = sum * (1.f / 512.f);
  float var = sq * (1.f / 512.f) - mu * mu;
  float rstd = rsqrtf(var + 1e-5f);
  unsigned int* orow =
      (unsigned int*)(xn + ((size_t)(b * 1024 + p0 + pix)) * 512);
#pragma unroll
  for (int i = 0; i < 16; ++i) {
    int dw = i * 16 + j;  // dword index 0..255
    int c0 = 2 * dw, c1 = 2 * dw + 1;
    float v0 = (tile[c0 * 17 + pix] - mu) * rstd * wsh[c0] + bsh[c0];
    float v1 = (tile[c1 * 17 + pix] - mu) * rstd * wsh[c1] + bsh[c1];
    orow[dw] = pack2(v0, v1);
  }
}

// ---------------------------------------------------------------------------
// QKV GEMM: C = A * B^T, A=xn (8192x512), B=qkv_w (1536x512). Tile 128x128,
// BK=32, double-buffered global_load_lds staging, one barrier/iter.
// LDS granule swizzle (both-sides-or-neither): chunk (r, g) stores the
// global granule g ^ f(r), f(r) = (r>>1)&3, via pre-swizzled SOURCE address;
// fragment reads fetch slot (quad ^ f(row)).
// Epilogue: +bias, q pre-scaled by QSCALE; q/k scattered (b,h,p,d); V blocks
// transposed through LDS then stored as coalesced 128B vT rows (b,h,d,p).
// vT COLUMN ORDER IS PERMUTED: within each 16-pixel group, p-bit2 and p-bit3
// are swapped (stored order {0-3,8-11,4-7,12-15}). This makes the attention
// PV B-fragment (k = (lane>>5)*8+j of mfma_32x32x16) line up with the
// Sᵀ C-layout (row=(reg&3)+8*(reg>>2)+4*(lane>>5)) with no cross-lane moves.
// ---------------------------------------------------------------------------
__global__ __launch_bounds__(256, 3) void gemm_qkv(
    const bf16* __restrict__ A, const bf16* __restrict__ Bm,
    const float* __restrict__ bias, bf16* __restrict__ oq,
    bf16* __restrict__ okk, bf16* __restrict__ ov) {
  // layout: A buf0 [0,4096), A buf1 [4096,8192), B buf0 [8192,12288),
  // B buf1 [12288,16384). Reused whole as V-transpose scratch in epilogue.
  __shared__ bf16 smem[16384];  // 32KB
  const int t = threadIdx.x;
  const int lane = t & 63, w = t >> 6;
  const int quad = lane >> 4, r16 = lane & 15;
  const int wm = w >> 1, wn = w & 1;
  // panel swizzle: 8 m-tiles x 12 n-tiles per panel
  const int pid = blockIdx.x;
  const int panel = pid / 96, within = pid % 96;
  const int m0 = (panel * 8 + (within & 7)) * 128;
  const int n0 = (within >> 3) * 128;
  int sr[2], sc[2];
#pragma unroll
  for (int j = 0; j < 2; ++j) {
    int c = (w * 2 + j) * 64 + lane;
    int r = c >> 2, g = c & 3;
    sr[j] = r;                         // row 0..127
    sc[j] = (g ^ ((r >> 1) & 3)) * 8;  // pre-swizzled source granule
  }
  const int gx = (r16 >> 1) & 3;  // lane-uniform read-side granule xor
  f32x4 acc[4][4] = {};
  // prologue: stage k-tile 0 into buffer 0
#pragma unroll
  for (int j = 0; j < 2; ++j) {
    gl16(&A[(size_t)(m0 + sr[j]) * 512 + sc[j]], &smem[(w * 2 + j) * 512]);
    gl16(&Bm[(size_t)(n0 + sr[j]) * 512 + sc[j]],
         &smem[8192 + (w * 2 + j) * 512]);
  }
  __syncthreads();
  for (int it = 0; it < 16; ++it) {
    const int cur = it & 1, nxt = cur ^ 1;
    if (it < 15) {
      int k1 = (it + 1) * 32;
#pragma unroll
      for (int j = 0; j < 2; ++j) {
        gl16(&A[(size_t)(m0 + sr[j]) * 512 + k1 + sc[j]],
             &smem[nxt * 4096 + (w * 2 + j) * 512]);
        gl16(&Bm[(size_t)(n0 + sr[j]) * 512 + k1 + sc[j]],
             &smem[8192 + nxt * 4096 + (w * 2 + j) * 512]);
      }
    }
    const bf16* ac = &smem[cur * 4096];
    const bf16* bc = &smem[8192 + cur * 4096];
    bf16x8 af[4], bfr[4];
#pragma unroll
    for (int i = 0; i < 4; ++i) {
      int row = wm * 64 + i * 16 + r16;
      af[i] = *(const bf16x8*)&ac[row * 32 + (quad ^ gx) * 8];
    }
#pragma unroll
    for (int i = 0; i < 4; ++i) {
      int row = wn * 64 + i * 16 + r16;
      bfr[i] = *(const bf16x8*)&bc[row * 32 + (quad ^ gx) * 8];
    }
#pragma unroll
    for (int tm = 0; tm < 4; ++tm)
#pragma unroll
      for (int tn = 0; tn < 4; ++tn)
        acc[tm][tn] = MFMA16(af[tm], bfr[tn], acc[tm][tn]);
    __syncthreads();
  }
  if (n0 < 1024) {
    // q / k blocks: direct scatter (d-contiguous 32B segments)
#pragma unroll
    for (int tm = 0; tm < 4; ++tm) {
#pragma unroll
      for (int tn = 0; tn < 4; ++tn) {
        int n = n0 + wn * 64 + tn * 16 + r16;
        float bn = bias[n];
        int comp = n >> 9, h = (n >> 6) & 7, d = n & 63;
#pragma unroll
        for (int r = 0; r < 4; ++r) {
          int m = m0 + wm * 64 + tm * 16 + quad * 4 + r;
          float v = acc[tm][tn][r] + bn;
          int b = m >> 10, p = m & 1023;
          size_t base = ((size_t)(b * 8 + h)) * 65536;
          if (comp == 0)
            oq[base + (size_t)p * 64 + d] = (bf16)(v * QSCALE);
          else
            okk[base + (size_t)p * 64 + d] = (bf16)v;
        }
      }
    }
  } else {
    // V block: per-wave LDS transpose (64d x 64p, stride 64, xor-swizzled at
    // 8-elem granules) then coalesced 128B-row stores of vT (b,h,d,p).
    // p-bit2<->bit3 column permutation baked in (granule tm*2+(quad&1),
    // offset (quad>>1)*4).
    bf16* tb = &smem[w * 4096];
#pragma unroll
    for (int tn = 0; tn < 4; ++tn) {
      int n = n0 + wn * 64 + tn * 16 + r16;
      float bn = bias[n];
      int row = tn * 16 + r16;  // d_local
#pragma unroll
      for (int tm = 0; tm < 4; ++tm) {
        f32x4 a = acc[tm][tn];
        uint2 pk;
        pk.x = pack2(a[0] + bn, a[1] + bn);
        pk.y = pack2(a[2] + bn, a[3] + bn);
        int g = (tm * 2 + (quad & 1)) ^ (row & 7);
        *(uint2*)&tb[row * 64 + g * 8 + (quad >> 1) * 4] = pk;
      }
    }
    // wave-private region: no barrier needed (lgkmcnt orders write->read)
    const int h = ((n0 - 1024) >> 6) + wn;
    const int mw = m0 + wm * 64;
    const int b = mw >> 10;
    bf16* vbase = ov + ((size_t)(b * 8 + h)) * 65536 + (mw & 1023);
#pragma unroll
    for (int pass = 0; pass < 8; ++pass) {
      int row = pass * 8 + (lane >> 3);
      int g = (lane & 7) ^ (row & 7);
      uint4 vd = *(uint4*)&tb[row * 64 + g * 8];
      *(uint4*)&vbase[(size_t)row * 1024 + (lane & 7) * 8] = vd;
    }
  }
}

// ---------------------------------------------------------------------------
// Proj GEMM: C = W * A^T, W=proj_w (512x512), A=attn out (8192x512).
// Tile 64x64 (grid 8x128 = 1024 blocks), BK=64, double-buffered swizzled
// global_load_lds staging. Epilogue: +bias[m] +residual, fp32 out (B,C,HW).
// ---------------------------------------------------------------------------
__global__ __launch_bounds__(256, 4) void gemm_proj(
    const bf16* __restrict__ Wm, const bf16* __restrict__ A,
    const float* __restrict__ bias, const float* __restrict__ resid,
    float* __restrict__ op) {
  __shared__ bf16 ash[2][64 * 64];
  __shared__ bf16 bsh[2][64 * 64];
  const int t = threadIdx.x;
  const int lane = t & 63, w = t >> 6;
  const int quad = lane >> 4, r16 = lane & 15;
  const int wm = w >> 1, wn = w & 1;
  const int m0 = blockIdx.x * 64, n0 = blockIdx.y * 64;
  int soff[2], sr[2];
#pragma unroll
  for (int j = 0; j < 2; ++j) {
    int c = (w * 2 + j) * 64 + lane;
    int r = c >> 3, cc = c & 7;
    sr[j] = r;
    soff[j] = (cc ^ (r & 7)) * 8;
  }
  f32x4 acc[2][2] = {};
  // prologue: stage k-tile 0 into buffer 0
#pragma unroll
  for (int j = 0; j < 2; ++j) {
    gl16(&Wm[(size_t)(m0 + sr[j]) * 512 + soff[j]], &ash[0][(w * 2 + j) * 512]);
    gl16(&A[(size_t)(n0 + sr[j]) * 512 + soff[j]], &bsh[0][(w * 2 + j) * 512]);
  }
  __syncthreads();
  for (int it = 0; it < 8; ++it) {
    const int cur = it & 1, nxt = cur ^ 1;
    if (it < 7) {
      int k1 = (it + 1) * 64;
#pragma unroll
      for (int j = 0; j < 2; ++j) {
        gl16(&Wm[(size_t)(m0 + sr[j]) * 512 + k1 + soff[j]],
             &ash[nxt][(w * 2 + j) * 512]);
        gl16(&A[(size_t)(n0 + sr[j]) * 512 + k1 + soff[j]],
             &bsh[nxt][(w * 2 + j) * 512]);
      }
    }
#pragma unroll
    for (int kc = 0; kc < 2; ++kc) {
      bf16x8 af[2], bfr[2];
#pragma unroll
      for (int i = 0; i < 2; ++i) {
        int row = wm * 32 + i * 16 + r16;
        af[i] = *(const bf16x8*)&ash[cur][row * 64 +
                                          ((kc * 4 + quad) ^ (r16 & 7)) * 8];
      }
#pragma unroll
      for (int i = 0; i < 2; ++i) {
        int row = wn * 32 + i * 16 + r16;
        bfr[i] = *(const bf16x8*)&bsh[cur][row * 64 +
                                           ((kc * 4 + quad) ^ (r16 & 7)) * 8];
      }
#pragma unroll
      for (int tm = 0; tm < 2; ++tm)
#pragma unroll
        for (int tn = 0; tn < 2; ++tn)
          acc[tm][tn] = MFMA16(af[tm], bfr[tn], acc[tm][tn]);
    }
    __syncthreads();
  }
#pragma unroll
  for (int tm = 0; tm < 2; ++tm) {
#pragma unroll
    for (int tn = 0; tn < 2; ++tn) {
      int n = n0 + wn * 32 + tn * 16 + r16;
      int b = n >> 10, p = n & 1023;
#pragma unroll
      for (int r = 0; r < 4; ++r) {
        int m = m0 + wm * 32 + tm * 16 + quad * 4 + r;
        size_t idx = ((size_t)(b * 512 + m)) * 1024 + p;
        op[idx] = acc[tm][tn][r] + bias[m] + resid[idx];
      }
    }
  }
}

// ---------------------------------------------------------------------------
// Flash attention, 32x32x16-MFMA, 32 q-rows/wave (measured-best geometry:
// 128q/block, 256 thr, 2 blocks/CU, dbuf 64-kv tiles), fexp2 softmax.
// Swapped QK^T: S^T = mfma(K, Q) puts q = lane&31; each lane owns a full
// 32-kv slice of one P row and softmax/P-pack is entirely in-register.
// Falsified alternatives (kept for the record): 64q/wave ILP (R5), wave-group
// kv-split (R6), counted-vmcnt triple-buffer (R7), hand cvt_pk + setprio
// (R8), 128-kv tiles (R9), 2-wave barrier domains (R11) -- all null or
// negative vs this structure.
// Grid (64 bh, 8 qt): id%8 = bh%8 keeps one bh's K/V on one XCD L2.
// ---------------------------------------------------------------------------
__global__ __launch_bounds__(256, 2) void attn_kernel(
    const bf16* __restrict__ q, const bf16* __restrict__ k,
    const bf16* __restrict__ vT, bf16* __restrict__ o) {
  __shared__ bf16 kt[2][64 * 64];  // 2x8KB K tiles (kv-row major, swizzled)
  __shared__ bf16 vt[2][64 * 64];  // 2x8KB vT tiles (d-row major, swizzled)
  const int t = threadIdx.x;
  const int lane = t & 63, w = t >> 6;
  const int l31 = lane & 31, hi = lane >> 5;
  const int bh = blockIdx.x;
  const int qt0 = blockIdx.y * 128;
  const bf16* qb = q + (size_t)bh * 65536;
  const bf16* kb = k + (size_t)bh * 65536;
  const bf16* vb = vT + (size_t)bh * 65536;
  // Q as B-fragment: col = q = lane&31, k(=d) = ks*16 + hi*8 + j
  const int qrow = qt0 + w * 32 + l31;
  bf16x8 qf[4];
#pragma unroll
  for (int ks = 0; ks < 4; ++ks)
    qf[ks] = *(const bf16x8*)&qb[(size_t)qrow * 64 + ks * 16 + hi * 8];
  // staging: 512 chunks/tile; wave w issues j=0,1; chunk c=(w*2+j)*64+lane
  int offk[2], offv[2];
#pragma unroll
  for (int j = 0; j < 2; ++j) {
    int c = (w * 2 + j) * 64 + lane;
    int r = c >> 3, cc = c & 7;
    int sw = (cc ^ (r & 7)) * 8;
    offk[j] = r * 64 + sw;    // K: row=kv (stride 64)
    offv[j] = r * 1024 + sw;  // vT: row=d (stride 1024)
  }
  f32x16 oacc[2] = {};  // O[q=(reg&3)+8*(reg>>2)+4*hi][d=mf*32+l31]
  float rsum = 0.f;     // full exp row-sum for q=l31 (this hi-half's kv)
  const int swz = l31 & 7;
  // prologue: stage tile 0
#pragma unroll
  for (int j = 0; j < 2; ++j) {
    gl16(&kb[offk[j]], &kt[0][(w * 2 + j) * 512]);
    gl16(&vb[offv[j]], &vt[0][(w * 2 + j) * 512]);
  }
  __syncthreads();
  for (int it = 0; it < 16; ++it) {
    const int cur = it & 1, nxt = cur ^ 1;
    if (it < 15) {
      int kv1 = (it + 1) * 64;
#pragma unroll
      for (int j = 0; j < 2; ++j) {
        gl16(&kb[(size_t)kv1 * 64 + offk[j]], &kt[nxt][(w * 2 + j) * 512]);
        gl16(&vb[(size_t)kv1 + offv[j]], &vt[nxt][(w * 2 + j) * 512]);
      }
    }
    const bf16* ktc = kt[cur];
    const bf16* vtc = vt[cur];
    // S^T[kv][q] = sum_d K[kv][d] Q[q][d]: two 32-kv tiles, 4 k-steps each.
    f32x16 sT[2] = {};
#pragma unroll
    for (int T = 0; T < 2; ++T) {
      const bf16* kr = &ktc[(T * 32 + l31) * 64];
#pragma unroll
      for (int ks = 0; ks < 4; ++ks) {
        bf16x8 kf = *(const bf16x8*)&kr[((ks * 2 + hi) ^ swz) * 8];
        sT[T] = MFMA32(kf, qf[ks], sT[T]);
      }
    }
    // max-free softmax numerator, all in-register (q = l31 for every reg)
#pragma unroll
    for (int T = 0; T < 2; ++T)
#pragma unroll
      for (int r = 0; r < 16; ++r) {
        float p = fexp2(sT[T][r]);
        sT[T][r] = p;
        rsum += p;
      }
    // PV: 4 chunks of 16 kv. P A-frag packs straight from regs; its k-slot
    // order (hi=0:{0-3,8-11}, hi=1:{4-7,12-15}) matches the permuted vT.
#pragma unroll
    for (int c4 = 0; c4 < 4; ++c4) {
      const int T = c4 >> 1, b0 = (c4 & 1) * 8;
      uint4 pui;
      pui.x = pack2(sT[T][b0 + 0], sT[T][b0 + 1]);
      pui.y = pack2(sT[T][b0 + 2], sT[T][b0 + 3]);
      pui.z = pack2(sT[T][b0 + 4], sT[T][b0 + 5]);
      pui.w = pack2(sT[T][b0 + 6], sT[T][b0 + 7]);
      bf16x8 pf = __builtin_bit_cast(bf16x8, pui);
#pragma unroll
      for (int mf = 0; mf < 2; ++mf) {
        const bf16* vr = &vtc[(mf * 32 + l31) * 64];
        bf16x8 vf = *(const bf16x8*)&vr[((c4 * 2 + hi) ^ swz) * 8];
        oacc[mf] = MFMA32(pf, vf, oacc[mf]);
      }
    }
    __syncthreads();  // all waves done with cur before it's restaged
  }
  // combine the two hi-half partial row sums (same q = l31)
  rsum += __shfl_xor(rsum, 32);
  float inv = 1.f / rsum;
  const int b = bh >> 3, h = bh & 7;
#pragma unroll
  for (int r = 0; r < 16; ++r) {
    const int ql = (r & 3) + 8 * (r >> 2) + 4 * hi;
    float invq = __shfl(inv, ql);  // lane ql holds inv for q-row ql
    const int p = qt0 + w * 32 + ql;
    const size_t base = ((size_t)(b * 1024 + p)) * 512 + h * 64;
#pragma unroll
    for (int mf = 0; mf < 2; ++mf)
      o[base + mf * 32 + l31] = (bf16)(oacc[mf][r] * invq);
  }
}

// ---------------------------------------------------------------------------
extern "C" void kernel_launch(void* const* d_in, const int* in_sizes, int n_in,
                              void* d_out, int out_size, void* d_ws,
                              size_t ws_size, hipStream_t stream) {
  (void)in_sizes;
  (void)n_in;
  (void)out_size;
  (void)ws_size;
  const float* x = (const float*)d_in[0];
  const float* lnw = (const float*)d_in[1];
  const float* lnb = (const float*)d_in[2];
  const float* qkvw = (const float*)d_in[3];
  const float* qkvb = (const float*)d_in[4];
  const float* projw = (const float*)d_in[5];
  const float* projb = (const float*)d_in[6];
  float* out = (float*)d_out;

  const size_t NELEM = 4194304;  // 8192 * 512
  bf16* wc = (bf16*)d_ws;        // qkvw_c [0,786432) projw_c [786432,1048576)
  bf16* xn = wc + 1048576;       // 8 MB; reused as attention output
  bf16* qws = xn + NELEM;        // 8 MB
  bf16* kws = qws + NELEM;       // 8 MB
  bf16* vws = kws + NELEM;       // 8 MB (transposed+col-permuted: b,h,d,p')
  bf16* aws = xn;                // reuse: xn dead after QKV gemm

  prep_kernel<<<dim3(1536), dim3(256), 0, stream>>>(qkvw, projw, wc, x, lnw,
                                                    lnb, xn);
  gemm_qkv<<<dim3(768), dim3(256), 0, stream>>>(xn, wc, qkvb, qws, kws, vws);
  attn_kernel<<<dim3(64, 8), dim3(256), 0, stream>>>(qws, kws, vws, aws);
  gemm_proj<<<dim3(8, 128), dim3(256), 0, stream>>>(wc + 786432, aws, projb, x,
                                                    out);
}